// Round 1
// baseline (468.564 us; speedup 1.0000x reference)
//
#include <hip/hip_runtime.h>
#include <hip/hip_bf16.h>

// MessagePassingLayer: N=50000 nodes, E=800000 edges, F=H=128.
// out = swish([nodes | segsum(swish([n[s]|n[r]|e] @ Wm1 + bm1) @ Wm2 + bm2)] @ Wu1 + bu1) @ Wu2 + bu2
//
// Restructure: msg_in@Wm1 = Pa[snd] + Pb[rcv] + edges@Wm1c  where P = nodes@[Wm1a|Wm1b] precomputed.
// All GEMMs: bf16 MFMA 16x16x32, fp32 accum. 4 waves/block, 64x64 wave tile, 4x4 frags.
// A-frags loaded from global fp32 -> cvt bf16 in regs. B-frags from pre-transposed bf16 WT[n][k] in L2.

typedef __bf16 bf16_t;
typedef __bf16 bf16x8 __attribute__((ext_vector_type(8)));
typedef float f32x4 __attribute__((ext_vector_type(4)));

#define MFMA16(a, b, c) __builtin_amdgcn_mfma_f32_16x16x32_bf16((a), (b), (c), 0, 0, 0)

__device__ __forceinline__ bf16x8 cvt_bf16x8(f32x4 lo, f32x4 hi) {
  bf16x8 r;
  r[0] = (bf16_t)lo[0]; r[1] = (bf16_t)lo[1]; r[2] = (bf16_t)lo[2]; r[3] = (bf16_t)lo[3];
  r[4] = (bf16_t)hi[0]; r[5] = (bf16_t)hi[1]; r[6] = (bf16_t)hi[2]; r[7] = (bf16_t)hi[3];
  return r;
}

__device__ __forceinline__ float swishf(float x) { return x / (1.0f + __expf(-x)); }

// ---------------- weight prep: bf16 + transpose to WT[n][k] ----------------
__global__ void prep_kernel(const float* __restrict__ Wm1, const float* __restrict__ Wm2,
                            const float* __restrict__ Wu1, const float* __restrict__ Wu2,
                            bf16_t* __restrict__ WmabT, bf16_t* __restrict__ Wm1cT,
                            bf16_t* __restrict__ Wm2T, bf16_t* __restrict__ Wu1aT,
                            bf16_t* __restrict__ Wu1bT, bf16_t* __restrict__ Wu2T) {
  const int t0 = blockIdx.x * blockDim.x + threadIdx.x;
  const int stride = gridDim.x * blockDim.x;
  for (int i = t0; i < 256 * 128; i += stride) {
    const int n = i >> 7, k = i & 127;
    const float v = (n < 128) ? Wm1[k * 128 + n] : Wm1[(128 + k) * 128 + (n - 128)];
    WmabT[i] = (bf16_t)v;
  }
  for (int i = t0; i < 128 * 128; i += stride) {
    const int n = i >> 7, k = i & 127;
    Wm1cT[i] = (bf16_t)Wm1[(256 + k) * 128 + n];
    Wm2T[i]  = (bf16_t)Wm2[k * 128 + n];
    Wu1aT[i] = (bf16_t)Wu1[k * 128 + n];
    Wu1bT[i] = (bf16_t)Wu1[(128 + k) * 128 + n];
    Wu2T[i]  = (bf16_t)Wu2[k * 128 + n];
  }
}

// ---------------- node_pre: P[:,0:128] = nodes@Wm1a, P[:,128:256] = nodes@Wm1b ----------------
__global__ __launch_bounds__(256) void node_pre_kernel(const float* __restrict__ nodes,
                                                       const bf16_t* __restrict__ WmabT,
                                                       float* __restrict__ P, const int nN) {
  const int tid = threadIdx.x;
  const int l = tid & 63, w = tid >> 6;
  const int wr = w >> 1, wc = w & 1;
  const int lr = l & 15, lk = l >> 4;
  const int half = blockIdx.y;
  const int r0 = blockIdx.x * 128 + wr * 64;
  const bf16_t* WT = WmabT + half * (128 * 128);

  f32x4 acc[4][4] = {};
#pragma unroll
  for (int ks = 0; ks < 4; ++ks) {
    bf16x8 a[4], b[4];
#pragma unroll
    for (int m = 0; m < 4; ++m) {
      int r = r0 + m * 16 + lr;
      if (r >= nN) r = nN - 1;
      const float* p = nodes + (long)r * 128 + ks * 32 + lk * 8;
      a[m] = cvt_bf16x8(*(const f32x4*)p, *(const f32x4*)(p + 4));
    }
#pragma unroll
    for (int n = 0; n < 4; ++n)
      b[n] = *(const bf16x8*)(WT + (wc * 64 + n * 16 + lr) * 128 + ks * 32 + lk * 8);
#pragma unroll
    for (int m = 0; m < 4; ++m)
#pragma unroll
      for (int n = 0; n < 4; ++n)
        acc[m][n] = MFMA16(a[m], b[n], acc[m][n]);
  }
#pragma unroll
  for (int m = 0; m < 4; ++m)
#pragma unroll
    for (int n = 0; n < 4; ++n)
#pragma unroll
      for (int j = 0; j < 4; ++j) {
        const int r = r0 + m * 16 + lk * 4 + j;
        const int c = wc * 64 + n * 16 + lr;
        if (r < nN) P[(long)r * 256 + half * 128 + c] = acc[m][n][j];
      }
}

// ---------------- edge kernel: 128 edges/block ----------------
__global__ __launch_bounds__(256) void edge_kernel(
    const float* __restrict__ edges, const int* __restrict__ senders,
    const int* __restrict__ receivers, const float* __restrict__ P,
    const float* __restrict__ bm1, const float* __restrict__ bm2,
    const bf16_t* __restrict__ Wm1cT, const bf16_t* __restrict__ Wm2T,
    float* __restrict__ agg) {
  __shared__ bf16_t Hs[128 * 128];  // 32 KB, XOR-swizzled, reused for H then msg
  __shared__ int snd[128], rcv[128];
  const int tid = threadIdx.x;
  const long e0 = (long)blockIdx.x * 128;
  if (tid < 128) {
    snd[tid] = senders[e0 + tid];
    rcv[tid] = receivers[e0 + tid];
  }
  const int l = tid & 63, w = tid >> 6;
  const int wr = w >> 1, wc = w & 1;
  const int lr = l & 15, lk = l >> 4;

  // GEMM1: edges @ Wm1c
  f32x4 acc[4][4] = {};
#pragma unroll
  for (int ks = 0; ks < 4; ++ks) {
    bf16x8 a[4], b[4];
#pragma unroll
    for (int m = 0; m < 4; ++m) {
      const float* p = edges + (e0 + wr * 64 + m * 16 + lr) * 128 + ks * 32 + lk * 8;
      a[m] = cvt_bf16x8(*(const f32x4*)p, *(const f32x4*)(p + 4));
    }
#pragma unroll
    for (int n = 0; n < 4; ++n)
      b[n] = *(const bf16x8*)(Wm1cT + (wc * 64 + n * 16 + lr) * 128 + ks * 32 + lk * 8);
#pragma unroll
    for (int m = 0; m < 4; ++m)
#pragma unroll
      for (int n = 0; n < 4; ++n)
        acc[m][n] = MFMA16(a[m], b[n], acc[m][n]);
  }
  __syncthreads();  // snd/rcv ready

  // epilogue: + Pa[snd] + Pb[rcv] + bm1, swish -> bf16 LDS (swizzled)
#pragma unroll
  for (int m = 0; m < 4; ++m)
#pragma unroll
    for (int j = 0; j < 4; ++j) {
      const int row = wr * 64 + m * 16 + lk * 4 + j;
      const long sb = (long)snd[row] * 256;
      const long rb = (long)rcv[row] * 256 + 128;
#pragma unroll
      for (int n = 0; n < 4; ++n) {
        const int col = wc * 64 + n * 16 + lr;
        const float x = acc[m][n][j] + P[sb + col] + P[rb + col] + bm1[col];
        Hs[row * 128 + (col ^ ((row & 7) << 3))] = (bf16_t)swishf(x);
      }
    }
  __syncthreads();

  // GEMM2: H @ Wm2
  f32x4 acc2[4][4] = {};
#pragma unroll
  for (int ks = 0; ks < 4; ++ks) {
    bf16x8 a[4], b[4];
#pragma unroll
    for (int m = 0; m < 4; ++m) {
      const int r = wr * 64 + m * 16 + lr;
      a[m] = *(const bf16x8*)&Hs[r * 128 + ((ks * 32 + lk * 8) ^ ((r & 7) << 3))];
    }
#pragma unroll
    for (int n = 0; n < 4; ++n)
      b[n] = *(const bf16x8*)(Wm2T + (wc * 64 + n * 16 + lr) * 128 + ks * 32 + lk * 8);
#pragma unroll
    for (int m = 0; m < 4; ++m)
#pragma unroll
      for (int n = 0; n < 4; ++n)
        acc2[m][n] = MFMA16(a[m], b[n], acc2[m][n]);
  }
  __syncthreads();  // all Hs reads done before overwrite

  // messages (+bm2) -> LDS (bf16, swizzled)
#pragma unroll
  for (int m = 0; m < 4; ++m)
#pragma unroll
    for (int n = 0; n < 4; ++n)
#pragma unroll
      for (int j = 0; j < 4; ++j) {
        const int row = wr * 64 + m * 16 + lk * 4 + j;
        const int col = wc * 64 + n * 16 + lr;
        Hs[row * 128 + (col ^ ((row & 7) << 3))] = (bf16_t)(acc2[m][n][j] + bm2[col]);
      }
  __syncthreads();

  // segmented reduction over sorted receivers; one atomic per (run, col)
  const int col = tid & 127;
  const int rbeg = (tid >> 7) * 64;
  float sum = 0.f;
  int cur = rcv[rbeg];
#pragma unroll 1
  for (int r = rbeg; r < rbeg + 64; ++r) {
    const int rc = rcv[r];
    if (rc != cur) {
      unsafeAtomicAdd(&agg[(long)cur * 128 + col], sum);
      sum = 0.f;
      cur = rc;
    }
    sum += (float)Hs[r * 128 + (col ^ ((r & 7) << 3))];
  }
  unsafeAtomicAdd(&agg[(long)cur * 128 + col], sum);
}

// ---------------- node_out: swish(nodes@Wu1a + agg@Wu1b + bu1) @ Wu2 + bu2 ----------------
__global__ __launch_bounds__(256) void node_out_kernel(
    const float* __restrict__ nodes, const float* __restrict__ agg,
    const float* __restrict__ bu1, const float* __restrict__ bu2,
    const bf16_t* __restrict__ Wu1aT, const bf16_t* __restrict__ Wu1bT,
    const bf16_t* __restrict__ Wu2T, float* __restrict__ out, const int nN) {
  __shared__ bf16_t Hs[128 * 128];
  const int tid = threadIdx.x;
  const int l = tid & 63, w = tid >> 6;
  const int wr = w >> 1, wc = w & 1;
  const int lr = l & 15, lk = l >> 4;
  const int r0 = blockIdx.x * 128;

  f32x4 acc[4][4] = {};
#pragma unroll
  for (int src = 0; src < 2; ++src) {
    const float* X = src ? agg : nodes;
    const bf16_t* WT = src ? Wu1bT : Wu1aT;
#pragma unroll
    for (int ks = 0; ks < 4; ++ks) {
      bf16x8 a[4], b[4];
#pragma unroll
      for (int m = 0; m < 4; ++m) {
        int r = r0 + wr * 64 + m * 16 + lr;
        if (r >= nN) r = nN - 1;
        const float* p = X + (long)r * 128 + ks * 32 + lk * 8;
        a[m] = cvt_bf16x8(*(const f32x4*)p, *(const f32x4*)(p + 4));
      }
#pragma unroll
      for (int n = 0; n < 4; ++n)
        b[n] = *(const bf16x8*)(WT + (wc * 64 + n * 16 + lr) * 128 + ks * 32 + lk * 8);
#pragma unroll
      for (int m = 0; m < 4; ++m)
#pragma unroll
        for (int n = 0; n < 4; ++n)
          acc[m][n] = MFMA16(a[m], b[n], acc[m][n]);
    }
  }

#pragma unroll
  for (int m = 0; m < 4; ++m)
#pragma unroll
    for (int n = 0; n < 4; ++n)
#pragma unroll
      for (int j = 0; j < 4; ++j) {
        const int row = wr * 64 + m * 16 + lk * 4 + j;
        const int col = wc * 64 + n * 16 + lr;
        const float x = acc[m][n][j] + bu1[col];
        Hs[row * 128 + (col ^ ((row & 7) << 3))] = (bf16_t)swishf(x);
      }
  __syncthreads();

  f32x4 acc2[4][4] = {};
#pragma unroll
  for (int ks = 0; ks < 4; ++ks) {
    bf16x8 a[4], b[4];
#pragma unroll
    for (int m = 0; m < 4; ++m) {
      const int r = wr * 64 + m * 16 + lr;
      a[m] = *(const bf16x8*)&Hs[r * 128 + ((ks * 32 + lk * 8) ^ ((r & 7) << 3))];
    }
#pragma unroll
    for (int n = 0; n < 4; ++n)
      b[n] = *(const bf16x8*)(Wu2T + (wc * 64 + n * 16 + lr) * 128 + ks * 32 + lk * 8);
#pragma unroll
    for (int m = 0; m < 4; ++m)
#pragma unroll
      for (int n = 0; n < 4; ++n)
        acc2[m][n] = MFMA16(a[m], b[n], acc2[m][n]);
  }

#pragma unroll
  for (int m = 0; m < 4; ++m)
#pragma unroll
    for (int n = 0; n < 4; ++n)
#pragma unroll
      for (int j = 0; j < 4; ++j) {
        const int row = r0 + wr * 64 + m * 16 + lk * 4 + j;
        const int col = wc * 64 + n * 16 + lr;
        if (row < nN) out[(long)row * 128 + col] = acc2[m][n][j] + bu2[col];
      }
}

extern "C" void kernel_launch(void* const* d_in, const int* in_sizes, int n_in,
                              void* d_out, int out_size, void* d_ws, size_t ws_size,
                              hipStream_t stream) {
  const float* nodes = (const float*)d_in[0];
  const float* edges = (const float*)d_in[1];
  const int* senders = (const int*)d_in[2];
  const int* receivers = (const int*)d_in[3];
  const float* Wm1 = (const float*)d_in[4];
  const float* bm1 = (const float*)d_in[5];
  const float* Wm2 = (const float*)d_in[6];
  const float* bm2 = (const float*)d_in[7];
  const float* Wu1 = (const float*)d_in[8];
  const float* bu1 = (const float*)d_in[9];
  const float* Wu2 = (const float*)d_in[10];
  const float* bu2 = (const float*)d_in[11];
  const int nN = in_sizes[0] / 128;  // 50000
  const int nE = in_sizes[1] / 128;  // 800000 (divisible by 128)

  // workspace layout (needs ~73.5 MB):
  //   P   : nN*256 f32 (51.2 MB)   -- [Pa | Pb]
  //   agg : nN*128 f32 (25.6 MB)
  //   bf16 transposed weights (~224 KB)
  char* ws = (char*)d_ws;
  float* P = (float*)ws;
  float* agg = (float*)(ws + (size_t)nN * 256 * 4);
  bf16_t* WmabT = (bf16_t*)(ws + (size_t)nN * 384 * 4);
  bf16_t* Wm1cT = WmabT + 256 * 128;
  bf16_t* Wm2T = Wm1cT + 128 * 128;
  bf16_t* Wu1aT = Wm2T + 128 * 128;
  bf16_t* Wu1bT = Wu1aT + 128 * 128;
  bf16_t* Wu2T = Wu1bT + 128 * 128;

  hipMemsetAsync(agg, 0, (size_t)nN * 128 * 4, stream);
  hipLaunchKernelGGL(prep_kernel, dim3(128), dim3(256), 0, stream,
                     Wm1, Wm2, Wu1, Wu2, WmabT, Wm1cT, Wm2T, Wu1aT, Wu1bT, Wu2T);
  hipLaunchKernelGGL(node_pre_kernel, dim3((nN + 127) / 128, 2), dim3(256), 0, stream,
                     nodes, WmabT, P, nN);
  hipLaunchKernelGGL(edge_kernel, dim3(nE / 128), dim3(256), 0, stream,
                     edges, senders, receivers, P, bm1, bm2, Wm1cT, Wm2T, agg);
  hipLaunchKernelGGL(node_out_kernel, dim3((nN + 127) / 128), dim3(256), 0, stream,
                     nodes, agg, bu1, bu2, Wu1aT, Wu1bT, Wu2T, (float*)d_out, nN);
}

// Round 2
// 380.074 us; speedup vs baseline: 1.2328x; 1.2328x over previous
//
#include <hip/hip_runtime.h>
#include <hip/hip_bf16.h>

// MessagePassingLayer: N=50000, E=800000, F=H=128.
// out = swish([nodes | segsum(swish([n[s]|n[r]|e]@Wm1+bm1)@Wm2+bm2)]@Wu1+bu1)@Wu2+bu2
//
// Restructures:
//  (1) msg pre-act = Pa[snd] + Pb[rcv] + edges@Wm1c + bm1, with P = nodes@[Wm1a|Wm1b] precomputed (bf16).
//  (2) Wm2 commutes with segsum:  agg@Wu1b = segsum(swish(x))@(Wm2@Wu1b) + deg*(bm2@Wu1b).
//      Edge kernel does only GEMM1+swish+segmented-reduce(S, deg). Wc=Wm2@Wu1b folded into node_out.
// All GEMMs: bf16 MFMA 16x16x32, fp32 accum, 4 waves/block, 64x64 wave tiles.

typedef __bf16 bf16_t;
typedef __bf16 bf16x8 __attribute__((ext_vector_type(8)));
typedef float f32x4 __attribute__((ext_vector_type(4)));

#define MFMA16(a, b, c) __builtin_amdgcn_mfma_f32_16x16x32_bf16((a), (b), (c), 0, 0, 0)

__device__ __forceinline__ bf16x8 cvt_bf16x8(f32x4 lo, f32x4 hi) {
  bf16x8 r;
  r[0] = (bf16_t)lo[0]; r[1] = (bf16_t)lo[1]; r[2] = (bf16_t)lo[2]; r[3] = (bf16_t)lo[3];
  r[4] = (bf16_t)hi[0]; r[5] = (bf16_t)hi[1]; r[6] = (bf16_t)hi[2]; r[7] = (bf16_t)hi[3];
  return r;
}

__device__ __forceinline__ float swishf(float x) { return x / (1.0f + __expf(-x)); }

// ---------------- weight prep ----------------
__global__ void prep_kernel(const float* __restrict__ Wm1, const float* __restrict__ Wm2,
                            const float* __restrict__ Wu1, const float* __restrict__ Wu2,
                            const float* __restrict__ bm2,
                            bf16_t* __restrict__ WmabT, bf16_t* __restrict__ Wm1cT,
                            bf16_t* __restrict__ Wu1aT, bf16_t* __restrict__ WcT,
                            bf16_t* __restrict__ Wu2T, float* __restrict__ bvec) {
  const int t0 = blockIdx.x * blockDim.x + threadIdx.x;
  const int stride = gridDim.x * blockDim.x;
  for (int i = t0; i < 256 * 128; i += stride) {
    const int n = i >> 7, k = i & 127;
    const float v = (n < 128) ? Wm1[k * 128 + n] : Wm1[(128 + k) * 128 + (n - 128)];
    WmabT[i] = (bf16_t)v;
  }
  for (int i = t0; i < 128 * 128; i += stride) {
    const int n = i >> 7, k = i & 127;
    Wm1cT[i] = (bf16_t)Wm1[(256 + k) * 128 + n];
    Wu1aT[i] = (bf16_t)Wu1[k * 128 + n];
    Wu2T[i]  = (bf16_t)Wu2[k * 128 + n];
  }
  // Wc = Wm2 @ Wu1b, stored transposed: WcT[c*128+r] = sum_k Wm2[r,k] * Wu1[128+k, c]
  for (int i = t0; i < 128 * 128; i += stride) {
    const int r = i >> 7, c = i & 127;
    float acc = 0.f;
    for (int k = 0; k < 128; ++k) acc += Wm2[r * 128 + k] * Wu1[(128 + k) * 128 + c];
    WcT[c * 128 + r] = (bf16_t)acc;
  }
  if (t0 < 128) {
    float acc = 0.f;
    for (int k = 0; k < 128; ++k) acc += bm2[k] * Wu1[(128 + k) * 128 + t0];
    bvec[t0] = acc;
  }
}

// ---------------- node_pre: P[:,0:128]=nodes@Wm1a, P[:,128:256]=nodes@Wm1b (bf16) ----------------
__global__ __launch_bounds__(256) void node_pre_kernel(const float* __restrict__ nodes,
                                                       const bf16_t* __restrict__ WmabT,
                                                       bf16_t* __restrict__ P, const int nN) {
  const int tid = threadIdx.x;
  const int l = tid & 63, w = tid >> 6;
  const int wr = w >> 1, wc = w & 1;
  const int lr = l & 15, lk = l >> 4;
  const int half = blockIdx.y;
  const int r0 = blockIdx.x * 128 + wr * 64;
  const bf16_t* WT = WmabT + half * (128 * 128);

  f32x4 acc[4][4] = {};
#pragma unroll
  for (int ks = 0; ks < 4; ++ks) {
    bf16x8 a[4], b[4];
#pragma unroll
    for (int m = 0; m < 4; ++m) {
      int r = r0 + m * 16 + lr;
      if (r >= nN) r = nN - 1;
      const float* p = nodes + (long)r * 128 + ks * 32 + lk * 8;
      a[m] = cvt_bf16x8(*(const f32x4*)p, *(const f32x4*)(p + 4));
    }
#pragma unroll
    for (int n = 0; n < 4; ++n)
      b[n] = *(const bf16x8*)(WT + (wc * 64 + n * 16 + lr) * 128 + ks * 32 + lk * 8);
#pragma unroll
    for (int m = 0; m < 4; ++m)
#pragma unroll
      for (int n = 0; n < 4; ++n)
        acc[m][n] = MFMA16(a[m], b[n], acc[m][n]);
  }
#pragma unroll
  for (int m = 0; m < 4; ++m)
#pragma unroll
    for (int n = 0; n < 4; ++n)
#pragma unroll
      for (int j = 0; j < 4; ++j) {
        const int r = r0 + m * 16 + lk * 4 + j;
        const int c = wc * 64 + n * 16 + lr;
        if (r < nN) P[(long)r * 256 + half * 128 + c] = (bf16_t)acc[m][n][j];
      }
}

// ---------------- edge kernel: 128 edges/block ----------------
#define PSLD 136  // padded cols (272 B/row: 16B-aligned, 2-way max conflict on scalar reads)
__global__ __launch_bounds__(256, 4) void edge_kernel(
    const float* __restrict__ edges, const int* __restrict__ senders,
    const int* __restrict__ receivers, const bf16_t* __restrict__ P,
    const float* __restrict__ bm1, const bf16_t* __restrict__ Wm1cT,
    float* __restrict__ S, float* __restrict__ deg) {
  __shared__ bf16_t Ps[128 * PSLD];  // Psum = Pa[snd]+Pb[rcv]+bm1; reused in-place for H'
  __shared__ int snd[128], rcv[128];
  const int tid = threadIdx.x;
  const long e0 = (long)blockIdx.x * 128;
  if (tid < 128) {
    snd[tid] = senders[e0 + tid];
    rcv[tid] = receivers[e0 + tid];
  }
  __syncthreads();

  // Phase A: cooperative vectorized gather of Psum into LDS.
  // 2048 chunks of 8 cols; 16 consecutive lanes cover one full 256-B P row (coalesced).
#pragma unroll
  for (int i = 0; i < 8; ++i) {
    const int c = tid + i * 256;         // 0..2047
    const int row = c >> 4, k = c & 15;  // col base = k*8
    const bf16x8 pa = *(const bf16x8*)(P + (long)snd[row] * 256 + k * 8);
    const bf16x8 pb = *(const bf16x8*)(P + (long)rcv[row] * 256 + 128 + k * 8);
    const f32x4 b0 = *(const f32x4*)(bm1 + k * 8);
    const f32x4 b1 = *(const f32x4*)(bm1 + k * 8 + 4);
    bf16x8 o;
#pragma unroll
    for (int j = 0; j < 4; ++j) o[j] = (bf16_t)((float)pa[j] + (float)pb[j] + b0[j]);
#pragma unroll
    for (int j = 4; j < 8; ++j) o[j] = (bf16_t)((float)pa[j] + (float)pb[j] + b1[j - 4]);
    *(bf16x8*)&Ps[row * PSLD + k * 8] = o;
  }

  // GEMM1: edges @ Wm1c (independent of Ps -> overlaps gather latency before the barrier)
  const int l = tid & 63, w = tid >> 6;
  const int wr = w >> 1, wc = w & 1;
  const int lr = l & 15, lk = l >> 4;
  f32x4 acc[4][4] = {};
#pragma unroll
  for (int ks = 0; ks < 4; ++ks) {
    bf16x8 a[4], b[4];
#pragma unroll
    for (int m = 0; m < 4; ++m) {
      const float* p = edges + (e0 + wr * 64 + m * 16 + lr) * 128 + ks * 32 + lk * 8;
      a[m] = cvt_bf16x8(*(const f32x4*)p, *(const f32x4*)(p + 4));
    }
#pragma unroll
    for (int n = 0; n < 4; ++n)
      b[n] = *(const bf16x8*)(Wm1cT + (wc * 64 + n * 16 + lr) * 128 + ks * 32 + lk * 8);
#pragma unroll
    for (int m = 0; m < 4; ++m)
#pragma unroll
      for (int n = 0; n < 4; ++n)
        acc[m][n] = MFMA16(a[m], b[n], acc[m][n]);
  }
  __syncthreads();  // Psum complete

  // epilogue: x = acc + Psum; H' = swish(x) written back IN PLACE (same thread reads & writes)
#pragma unroll
  for (int m = 0; m < 4; ++m)
#pragma unroll
    for (int n = 0; n < 4; ++n)
#pragma unroll
      for (int j = 0; j < 4; ++j) {
        const int row = wr * 64 + m * 16 + lk * 4 + j;
        const int col = wc * 64 + n * 16 + lr;
        const float x = acc[m][n][j] + (float)Ps[row * PSLD + col];
        Ps[row * PSLD + col] = (bf16_t)swishf(x);
      }
  __syncthreads();

  // segmented reduction over sorted receivers: S[n] += sum H'[e], deg[n] += count
  const int col = tid & 127;
  const int rbeg = (tid >> 7) * 64;
  float sum = 0.f, cnt = 0.f;
  int cur = rcv[rbeg];
  for (int r = rbeg; r < rbeg + 64; ++r) {
    const int rc = rcv[r];
    if (rc != cur) {
      unsafeAtomicAdd(&S[(long)cur * 128 + col], sum);
      if (col == 0) unsafeAtomicAdd(&deg[cur], cnt);
      sum = 0.f; cnt = 0.f; cur = rc;
    }
    sum += (float)Ps[r * PSLD + col];
    cnt += 1.f;
  }
  unsafeAtomicAdd(&S[(long)cur * 128 + col], sum);
  if (col == 0) unsafeAtomicAdd(&deg[cur], cnt);
}

// ---------------- node_out: swish(nodes@Wu1a + S@Wc + deg*bvec + bu1) @ Wu2 + bu2 ----------------
__global__ __launch_bounds__(256) void node_out_kernel(
    const float* __restrict__ nodes, const float* __restrict__ S,
    const float* __restrict__ deg, const float* __restrict__ bvec,
    const float* __restrict__ bu1, const float* __restrict__ bu2,
    const bf16_t* __restrict__ Wu1aT, const bf16_t* __restrict__ WcT,
    const bf16_t* __restrict__ Wu2T, float* __restrict__ out, const int nN) {
  __shared__ bf16_t Hs[128 * 128];
  const int tid = threadIdx.x;
  const int l = tid & 63, w = tid >> 6;
  const int wr = w >> 1, wc = w & 1;
  const int lr = l & 15, lk = l >> 4;
  const int r0 = blockIdx.x * 128;

  f32x4 acc[4][4] = {};
#pragma unroll
  for (int src = 0; src < 2; ++src) {
    const float* X = src ? S : nodes;
    const bf16_t* WT = src ? WcT : Wu1aT;
#pragma unroll
    for (int ks = 0; ks < 4; ++ks) {
      bf16x8 a[4], b[4];
#pragma unroll
      for (int m = 0; m < 4; ++m) {
        int r = r0 + wr * 64 + m * 16 + lr;
        if (r >= nN) r = nN - 1;
        const float* p = X + (long)r * 128 + ks * 32 + lk * 8;
        a[m] = cvt_bf16x8(*(const f32x4*)p, *(const f32x4*)(p + 4));
      }
#pragma unroll
      for (int n = 0; n < 4; ++n)
        b[n] = *(const bf16x8*)(WT + (wc * 64 + n * 16 + lr) * 128 + ks * 32 + lk * 8);
#pragma unroll
      for (int m = 0; m < 4; ++m)
#pragma unroll
        for (int n = 0; n < 4; ++n)
          acc[m][n] = MFMA16(a[m], b[n], acc[m][n]);
    }
  }

#pragma unroll
  for (int m = 0; m < 4; ++m)
#pragma unroll
    for (int n = 0; n < 4; ++n)
#pragma unroll
      for (int j = 0; j < 4; ++j) {
        const int row = wr * 64 + m * 16 + lk * 4 + j;
        const int gr = r0 + row;
        const int col = wc * 64 + n * 16 + lr;
        const float dg = (gr < nN) ? deg[gr] : 0.f;
        const float x = acc[m][n][j] + bu1[col] + dg * bvec[col];
        Hs[row * 128 + (col ^ ((row & 7) << 3))] = (bf16_t)swishf(x);
      }
  __syncthreads();

  f32x4 acc2[4][4] = {};
#pragma unroll
  for (int ks = 0; ks < 4; ++ks) {
    bf16x8 a[4], b[4];
#pragma unroll
    for (int m = 0; m < 4; ++m) {
      const int r = wr * 64 + m * 16 + lr;
      a[m] = *(const bf16x8*)&Hs[r * 128 + ((ks * 32 + lk * 8) ^ ((r & 7) << 3))];
    }
#pragma unroll
    for (int n = 0; n < 4; ++n)
      b[n] = *(const bf16x8*)(Wu2T + (wc * 64 + n * 16 + lr) * 128 + ks * 32 + lk * 8);
#pragma unroll
    for (int m = 0; m < 4; ++m)
#pragma unroll
      for (int n = 0; n < 4; ++n)
        acc2[m][n] = MFMA16(a[m], b[n], acc2[m][n]);
  }

#pragma unroll
  for (int m = 0; m < 4; ++m)
#pragma unroll
    for (int n = 0; n < 4; ++n)
#pragma unroll
      for (int j = 0; j < 4; ++j) {
        const int row = r0 + wr * 64 + m * 16 + lk * 4 + j;
        const int col = wc * 64 + n * 16 + lr;
        if (row < nN) out[(long)row * 128 + col] = acc2[m][n][j] + bu2[col];
      }
}

extern "C" void kernel_launch(void* const* d_in, const int* in_sizes, int n_in,
                              void* d_out, int out_size, void* d_ws, size_t ws_size,
                              hipStream_t stream) {
  const float* nodes = (const float*)d_in[0];
  const float* edges = (const float*)d_in[1];
  const int* senders = (const int*)d_in[2];
  const int* receivers = (const int*)d_in[3];
  const float* Wm1 = (const float*)d_in[4];
  const float* bm1 = (const float*)d_in[5];
  const float* Wm2 = (const float*)d_in[6];
  const float* bm2 = (const float*)d_in[7];
  const float* Wu1 = (const float*)d_in[8];
  const float* bu1 = (const float*)d_in[9];
  const float* Wu2 = (const float*)d_in[10];
  const float* bu2 = (const float*)d_in[11];
  const int nN = in_sizes[0] / 128;  // 50000
  const int nE = in_sizes[1] / 128;  // 800000

  // workspace layout (~51.6 MB):
  //   P    : nN*256 bf16 (25.6 MB)  [Pa | Pb]
  //   S    : nN*128 f32  (25.6 MB)  segsum(swish) accumulator
  //   deg  : nN f32      (0.2 MB)
  //   weights: WmabT, Wm1cT, Wu1aT, WcT, Wu2T (bf16), bvec (f32)
  char* ws = (char*)d_ws;
  bf16_t* P = (bf16_t*)ws;
  float* S = (float*)(ws + (size_t)nN * 256 * 2);
  float* deg = S + (size_t)nN * 128;
  bf16_t* WmabT = (bf16_t*)(deg + nN);
  bf16_t* Wm1cT = WmabT + 256 * 128;
  bf16_t* Wu1aT = Wm1cT + 128 * 128;
  bf16_t* WcT = Wu1aT + 128 * 128;
  bf16_t* Wu2T = WcT + 128 * 128;
  float* bvec = (float*)(Wu2T + 128 * 128);

  hipMemsetAsync(S, 0, (size_t)nN * 129 * 4, stream);  // S + deg contiguous
  hipLaunchKernelGGL(prep_kernel, dim3(128), dim3(256), 0, stream,
                     Wm1, Wm2, Wu1, Wu2, bm2, WmabT, Wm1cT, Wu1aT, WcT, Wu2T, bvec);
  hipLaunchKernelGGL(node_pre_kernel, dim3((nN + 127) / 128, 2), dim3(256), 0, stream,
                     nodes, WmabT, P, nN);
  hipLaunchKernelGGL(edge_kernel, dim3(nE / 128), dim3(256), 0, stream,
                     edges, senders, receivers, P, bm1, Wm1cT, S, deg);
  hipLaunchKernelGGL(node_out_kernel, dim3((nN + 127) / 128), dim3(256), 0, stream,
                     nodes, S, deg, bvec, bu1, bu2, Wu1aT, WcT, Wu2T, (float*)d_out, nN);
}